// Round 12
// baseline (91.909 us; speedup 1.0000x reference)
//
#include <hip/hip_runtime.h>

#define NB 8192
#define OT_ELEMS (NB * 1024)   // floats of Ot, then Mt
#define EPSF 1e-10f

typedef __attribute__((ext_vector_type(4))) float f32x4;
typedef __attribute__((ext_vector_type(8))) short s16x8;   // 8 bf16 (4 VGPRs)

// Wave-local DS phase fence WITHOUT "memory" clobber (R9-R11 replay-proven).
#define SBAR() __builtin_amdgcn_sched_barrier(0)
#define LGK()  do { SBAR(); asm volatile("s_waitcnt lgkmcnt(0)"); SBAR(); } while (0)

#define MFMA_B16(A, B, C) __builtin_amdgcn_mfma_f32_16x16x32_bf16((A), (B), (C), 0, 0, 0)

// ---------------- Kernel 1: Cayley matrices M = (I-S)^-1 (I+S), stored ROW-major ----------------
__global__ void cayley_kernel(const float* __restrict__ Br,
                              const float* __restrict__ Bt,
                              const float* __restrict__ By,
                              float* __restrict__ M_out) {
  __shared__ float A[32][33];
  __shared__ float R[32][33];
  const float* B = (blockIdx.x == 0) ? Br : (blockIdx.x == 1) ? Bt : By;
  const int t = threadIdx.x;
  const int i = t >> 5, j = t & 31;
  float Lij = (j < i) ? B[i - 1 + j] : 0.0f;
  float Lji = (i < j) ? B[j - 1 + i] : 0.0f;
  float S = Lij - Lji;
  float eye = (i == j) ? 1.0f : 0.0f;
  A[i][j] = eye - S;   // I - S
  R[i][j] = eye + S;   // I + S
  __syncthreads();
  for (int p = 0; p < 32; ++p) {
    float f = A[i][p] / A[p][p];
    __syncthreads();
    if (i != p) {
      A[i][j] -= f * A[p][j];
      R[i][j] -= f * R[p][j];
    }
    __syncthreads();
  }
  // ROW-major: slot0=MR(0), slot1=MT(1024), slot2=MY(2048)
  M_out[blockIdx.x * 1024 + i * 32 + j] = R[i][j] / A[i][i];
}

// ---- Kernel 1b: P = MT*MR (slot3), Q1 = MY*MT (slot4), Q2 = MY*P (slot5), fp32 row-major ----
__global__ void combine_kernel(float* __restrict__ ws) {
  __shared__ float sMR[1024], sMT[1024], sMY[1024], sP[1024];
  const int t = threadIdx.x;
  sMR[t] = ws[t];
  sMT[t] = ws[1024 + t];
  sMY[t] = ws[2048 + t];
  __syncthreads();
  const int i = t >> 5, j = t & 31;
  float p = 0.f, q1 = 0.f;
#pragma unroll
  for (int k = 0; k < 32; ++k) {
    p  = fmaf(sMT[i * 32 + k], sMR[k * 32 + j], p);
    q1 = fmaf(sMY[i * 32 + k], sMT[k * 32 + j], q1);
  }
  sP[i * 32 + j] = p;
  ws[3072 + i * 32 + j] = p;
  ws[4096 + i * 32 + j] = q1;
  __syncthreads();
  float q2 = 0.f;
#pragma unroll
  for (int k = 0; k < 32; ++k)
    q2 = fmaf(sMY[i * 32 + k], sP[k * 32 + j], q2);
  ws[5120 + i * 32 + j] = q2;
}

// fp32 -> bf16 hi/lo split
__device__ __forceinline__ void cvt_hilo8(const f32x4 f0, const f32x4 f1, s16x8& hi, s16x8& lo) {
  float f[8];
#pragma unroll
  for (int e = 0; e < 4; ++e) { f[e] = f0[e]; f[4 + e] = f1[e]; }
#pragma unroll
  for (int e = 0; e < 8; ++e) {
    unsigned u = __float_as_uint(f[e]);
    hi[e] = (short)(u >> 16);
    float ah = __uint_as_float(u & 0xffff0000u);
    lo[e] = (short)(__float_as_uint(f[e] - ah) >> 16);
  }
}

__device__ __forceinline__ void read_frag_lds(const float* sb, int off, s16x8& hi, s16x8& lo) {
  f32x4 f0 = *(const f32x4*)(sb + off);
  f32x4 f1 = *(const f32x4*)(sb + off + 4);
  cvt_hilo8(f0, f1, hi, lo);
}

// 3-MFMA split-precision product tile: acc = M(hi/lo) * B(hi/lo)
#define PROD3(ACC, MH, ML, BH, BL)             \
  do {                                         \
    ACC = MFMA_B16((ML), (BH), ACC);           \
    ACC = MFMA_B16((MH), (BL), ACC);           \
    ACC = MFMA_B16((MH), (BH), ACC);           \
  } while (0)

// ---------------- Kernel 2: one batch per wave; 5 parallel congruence chains, depth-1 ----------------
// U = sum wr[a]*m[a], V' = sum wsn[a](1-al[a])*m[a], cP = sum wsn[a]*al[a].
// Phit = (1-at)*MT X MT^T + at*P U P^T            (chains 1,2)
// Ot   = MY V' MY^T + cP(1-at)*Q1 X Q1^T + cP*at*Q2 U Q2^T   (chains 3,4,5)
// Mt[a] = (1-al[a])*m[a] + al[a]*Phit   (m kept in registers, no re-read)
__global__ __launch_bounds__(64) void spdsru_main(
    const float* __restrict__ X, const float* __restrict__ state,
    const float* __restrict__ WR, const float* __restrict__ Wt,
    const float* __restrict__ Wphi, const float* __restrict__ Ws,
    const float* __restrict__ Mg, float* __restrict__ out) {
  __shared__ __align__(16) float sb0[1184], sb1[1184], sb2[1184], sb3[1184], sb4[1184];
  const int lane = threadIdx.x;
  const int l15 = lane & 15, l4 = lane >> 4;
  const int i0 = (lane >> 3) << 2, j0 = (lane & 7) << 2;
  const int bid = blockIdx.x;
  const int batch = (bid & 7) * (NB >> 3) + (bid >> 3);   // XCD-contiguous

  // fragments: q0=MT, q1=P, q2=MY, q3=Q1, q4=Q2
  s16x8 Mh[5][2], Ml[5][2];
  {
    const int srcoff[5] = {1024, 3072, 2048, 4096, 5120};
#pragma unroll
    for (int q = 0; q < 5; ++q)
#pragma unroll
      for (int s = 0; s < 2; ++s) {
        const float* p = Mg + srcoff[q] + (16 * s + l15) * 32 + 8 * l4;
        cvt_hilo8(*(const f32x4*)p, *(const f32x4*)(p + 4), Mh[q][s], Ml[q][s]);
      }
  }

  // uniform scalar weights
  const float alpha[5] = {0.01f, 0.25f, 0.5f, 0.9f, 0.99f};
  float wr[5], va[5];
  float cP = 0.f;
  {
    float sR = 0.f, sS = 0.f, wq[5];
#pragma unroll
    for (int a = 0; a < 5; ++a) { float v = WR[a]; wr[a] = v * v; sR += v * v; }
#pragma unroll
    for (int a = 0; a < 5; ++a) { float v = Ws[a]; wq[a] = v * v; sS += v * v; }
    const float invR = 1.0f / (sR + EPSF), invS = 1.0f / (sS + EPSF);
#pragma unroll
    for (int a = 0; a < 5; ++a) {
      wr[a] *= invR;
      float w = wq[a] * invS;
      va[a] = w * (1.0f - alpha[a]);
      cP += w * alpha[a];
    }
  }
  const float wt2 = Wt[0] * Wt[0], wp2 = Wphi[0] * Wphi[0];
  const float at = wt2 / (wt2 + wp2 + EPSF);
  const float omat = 1.0f - at;
  const float cpo = cP * omat, cpa = cP * at;

  // loads: m[5] kept in registers to the end; X NT-loaded
  const float* stp = state + (size_t)batch * 5120;
  f32x4 m[5][4];
#pragma unroll
  for (int a = 0; a < 5; ++a)
#pragma unroll
    for (int r = 0; r < 4; ++r)
      m[a][r] = *(const f32x4*)(stp + a * 1024 + (i0 + r) * 32 + j0);
  const float* xp = X + (size_t)batch * 1024;
  f32x4 x[4];
#pragma unroll
  for (int r = 0; r < 4; ++r)
    x[r] = __builtin_nontemporal_load((const f32x4*)(xp + (i0 + r) * 32 + j0));

  // fold U, V'
  f32x4 U[4], V[4];
#pragma unroll
  for (int r = 0; r < 4; ++r) {
    f32x4 u = wr[0] * m[0][r], v = va[0] * m[0][r];
#pragma unroll
    for (int a = 1; a < 5; ++a) { u += wr[a] * m[a][r]; v += va[a] * m[a][r]; }
    U[r] = u; V[r] = v;
  }

  // ---- phase 1: stage X, U, V' col-major (stride 36) ----
#pragma unroll
  for (int c = 0; c < 4; ++c) {
    f32x4 cx = {x[0][c], x[1][c], x[2][c], x[3][c]};
    f32x4 cu = {U[0][c], U[1][c], U[2][c], U[3][c]};
    f32x4 cv = {V[0][c], V[1][c], V[2][c], V[3][c]};
    *(f32x4*)(sb0 + (j0 + c) * 36 + i0) = cx;
    *(f32x4*)(sb1 + (j0 + c) * 36 + i0) = cu;
    *(f32x4*)(sb2 + (j0 + c) * 36 + i0) = cv;
  }
  LGK();

  // ---- phase 2: B-frags for X, U, V ----
  s16x8 BXh[2], BXl[2], BUh[2], BUl[2], BVh[2], BVl[2];
#pragma unroll
  for (int s = 0; s < 2; ++s) {
    read_frag_lds(sb0, (16 * s + l15) * 36 + 8 * l4, BXh[s], BXl[s]);
    read_frag_lds(sb1, (16 * s + l15) * 36 + 8 * l4, BUh[s], BUl[s]);
    read_frag_lds(sb2, (16 * s + l15) * 36 + 8 * l4, BVh[s], BVl[s]);
  }
  LGK();

  // ---- phase 3: MFMA1 x60, each chain's g staged row-major right after compute ----
#define STAGE_G(SB, G)                                                      \
  do {                                                                      \
    _Pragma("unroll") for (int ms = 0; ms < 2; ++ms)                        \
      _Pragma("unroll") for (int ns = 0; ns < 2; ++ns)                      \
        _Pragma("unroll") for (int r = 0; r < 4; ++r)                       \
          (SB)[(16 * ms + 4 * l4 + r) * 36 + 16 * ns + l15] = G[ms][ns][r]; \
  } while (0)

  {
    f32x4 g[2][2];
#pragma unroll
    for (int ms = 0; ms < 2; ++ms)
#pragma unroll
      for (int ns = 0; ns < 2; ++ns) { f32x4 a = {0,0,0,0}; PROD3(a, Mh[0][ms], Ml[0][ms], BXh[ns], BXl[ns]); g[ms][ns] = a; }
    STAGE_G(sb0, g);   // gX1 = MT*X
#pragma unroll
    for (int ms = 0; ms < 2; ++ms)
#pragma unroll
      for (int ns = 0; ns < 2; ++ns) { f32x4 a = {0,0,0,0}; PROD3(a, Mh[1][ms], Ml[1][ms], BUh[ns], BUl[ns]); g[ms][ns] = a; }
    STAGE_G(sb1, g);   // gU1 = P*U
#pragma unroll
    for (int ms = 0; ms < 2; ++ms)
#pragma unroll
      for (int ns = 0; ns < 2; ++ns) { f32x4 a = {0,0,0,0}; PROD3(a, Mh[2][ms], Ml[2][ms], BVh[ns], BVl[ns]); g[ms][ns] = a; }
    STAGE_G(sb2, g);   // gV = MY*V'
#pragma unroll
    for (int ms = 0; ms < 2; ++ms)
#pragma unroll
      for (int ns = 0; ns < 2; ++ns) { f32x4 a = {0,0,0,0}; PROD3(a, Mh[3][ms], Ml[3][ms], BXh[ns], BXl[ns]); g[ms][ns] = a; }
    STAGE_G(sb3, g);   // gX2 = Q1*X
#pragma unroll
    for (int ms = 0; ms < 2; ++ms)
#pragma unroll
      for (int ns = 0; ns < 2; ++ns) { f32x4 a = {0,0,0,0}; PROD3(a, Mh[4][ms], Ml[4][ms], BUh[ns], BUl[ns]); g[ms][ns] = a; }
    STAGE_G(sb4, g);   // gU2 = Q2*U
  }
  LGK();

  // ---- phase 4: A-frags for Phit chains ----
  s16x8 A1h[2], A1l[2], A2h[2], A2l[2];
#pragma unroll
  for (int s = 0; s < 2; ++s) {
    read_frag_lds(sb0, (16 * s + l15) * 36 + 8 * l4, A1h[s], A1l[s]);
    read_frag_lds(sb1, (16 * s + l15) * 36 + 8 * l4, A2h[s], A2l[s]);
  }
  LGK();

  // ---- phase 5: Phit = omat*(gX1*MT^T) + at*(gU1*P^T) ; A-frags for Ot chains ----
  f32x4 ph[2][2];
#pragma unroll
  for (int ms = 0; ms < 2; ++ms)
#pragma unroll
    for (int ns = 0; ns < 2; ++ns) {
      f32x4 a0 = {0,0,0,0}, a1 = {0,0,0,0};
      PROD3(a0, A1h[ms], A1l[ms], Mh[0][ns], Ml[0][ns]);
      PROD3(a1, A2h[ms], A2l[ms], Mh[1][ns], Ml[1][ns]);
      ph[ms][ns] = omat * a0 + at * a1;
    }
  s16x8 A3h[2], A3l[2], A4h[2], A4l[2], A5h[2], A5l[2];
#pragma unroll
  for (int s = 0; s < 2; ++s) {
    read_frag_lds(sb2, (16 * s + l15) * 36 + 8 * l4, A3h[s], A3l[s]);
    read_frag_lds(sb3, (16 * s + l15) * 36 + 8 * l4, A4h[s], A4l[s]);
    read_frag_lds(sb4, (16 * s + l15) * 36 + 8 * l4, A5h[s], A5l[s]);
  }
  LGK();

  // ---- phase 6: Ot = gV*MY^T + cpo*(gX2*Q1^T) + cpa*(gU2*Q2^T) ; transpose-stage ph & ot ----
  f32x4 ot[2][2];
#pragma unroll
  for (int ms = 0; ms < 2; ++ms)
#pragma unroll
    for (int ns = 0; ns < 2; ++ns) {
      f32x4 a0 = {0,0,0,0}, a1 = {0,0,0,0}, a2 = {0,0,0,0};
      PROD3(a0, A3h[ms], A3l[ms], Mh[2][ns], Ml[2][ns]);
      PROD3(a1, A4h[ms], A4l[ms], Mh[3][ns], Ml[3][ns]);
      PROD3(a2, A5h[ms], A5l[ms], Mh[4][ns], Ml[4][ns]);
      ot[ms][ns] = a0 + cpo * a1 + cpa * a2;
    }
  STAGE_G(sb0, ph);
  STAGE_G(sb1, ot);
  LGK();

  // ---- phase 7: rowtile reads; EMA from registers; NT stores ----
  f32x4 ph4[4], ot4[4];
#pragma unroll
  for (int r = 0; r < 4; ++r) {
    ph4[r] = *(const f32x4*)(sb0 + (i0 + r) * 36 + j0);
    ot4[r] = *(const f32x4*)(sb1 + (i0 + r) * 36 + j0);
  }
  float* outMt = out + OT_ELEMS + (size_t)batch * 5120;
#pragma unroll
  for (int a = 0; a < 5; ++a) {
    const float al = alpha[a], om = 1.0f - al;
#pragma unroll
    for (int r = 0; r < 4; ++r) {
      f32x4 w = om * m[a][r] + al * ph4[r];
      __builtin_nontemporal_store(w, (f32x4*)(outMt + a * 1024 + (i0 + r) * 32 + j0));
    }
  }
  float* outOt = out + (size_t)batch * 1024;
#pragma unroll
  for (int r = 0; r < 4; ++r)
    __builtin_nontemporal_store(ot4[r], (f32x4*)(outOt + (i0 + r) * 32 + j0));
#undef STAGE_G
}

extern "C" void kernel_launch(void* const* d_in, const int* in_sizes, int n_in,
                              void* d_out, int out_size, void* d_ws, size_t ws_size,
                              hipStream_t stream) {
  const float* X     = (const float*)d_in[0];
  const float* state = (const float*)d_in[1];
  const float* WR    = (const float*)d_in[2];
  const float* Wt    = (const float*)d_in[3];
  const float* Wphi  = (const float*)d_in[4];
  const float* Ws    = (const float*)d_in[5];
  const float* Br    = (const float*)d_in[6];
  const float* Bt    = (const float*)d_in[7];
  const float* By    = (const float*)d_in[8];
  float* m_ws = (float*)d_ws;   // 6*1024 floats: MR, MT, MY, P, Q1, Q2 (row-major)
  float* outp = (float*)d_out;

  cayley_kernel<<<3, 1024, 0, stream>>>(Br, Bt, By, m_ws);
  combine_kernel<<<1, 1024, 0, stream>>>(m_ws);
  spdsru_main<<<NB, 64, 0, stream>>>(X, state, WR, Wt, Wphi, Ws, m_ws, outp);
}